// Round 6
// baseline (337.896 us; speedup 1.0000x reference)
//
#include <hip/hip_runtime.h>

// sbvr decode: decoded[g,l] = sum_s coeff_cache[coeff_idx[g], s] * ((bvr[g,s]>>l)&1)
// G = 4,194,304 groups, S = 4 sums, L = 16 elements/group, out = 64M fp32 (256 MB).
//
// v7: PERSISTENT DOUBLE-BUFFERED PIPELINE.
// Calibration (v5 repeat-3 diagnostic): harness overhead ~239 us fixed;
// T_kernel: v0 ~104 us, v6 (cooperative staging, 16->7 addrs/group) ~92 us,
// floor ~53 us. v5 counters: compulsory bytes both directions, 3.1 TB/s,
// VALU 26%, occ 83% -- supply-side arithmetic says we should sit at 6.3 TB/s,
// so the cap is STRUCTURAL. The harness fills hit 6.4 TB/s at 10% occupancy /
// 5% VALU: persistent few-wave loops with deep store queues. All our versions
// used ONE-SHOT waves (7 memory ops amid ~130 VALU instrs, then die): store
// pipeline never gets deep, and 65K waves each pay launch/setup/drain in
// non-memory time. v2's null (batching within one-shot waves) and v6's +12%
// (dedup only) both fit this model.
//
// Structure: 2048 blocks (8/CU, 16 KB LDS each -> 128 KB/CU, full occupancy),
// each block owns 2048 contiguous groups = 8 tiles x 256 groups.
// Per tile: stage(t+1) loads issued BEFORE compute(t), so idx/bvr/gather of
// the next tile are in flight under the current tile's 16 NT stores; LDS
// double-buffer, ONE barrier per tile.
//   stage:   1 idx + 1 bvr(16B) + 1 gather(16B) per group (v6 dedup kept)
//   compute: 4 passes, coeffs/bits broadcast from LDS, contiguous f32x4 NT
//            stores (4 KB/wave, same coalescing as v6).
//
// NOTE: __builtin_nontemporal_* requires native ext_vector_type, not the
// HIP_vector_type structs (int4/float4) — hence i32x4/f32x4 below.

#define NUM_SUMS 4
#define BVR_LEN 16

typedef int   i32x4 __attribute__((ext_vector_type(4)));
typedef float f32x4 __attribute__((ext_vector_type(4)));

static constexpr int NUM_GROUPS  = (8192 * 8192) / 16;   // 4,194,304
static constexpr int BLOCK       = 256;
static constexpr int G_TILE      = 256;                  // groups per tile
static constexpr int GRID        = 2048;                 // 8 blocks/CU
static constexpr int G_PER_BLK   = NUM_GROUPS / GRID;    // 2048
static constexpr int TILES       = G_PER_BLK / G_TILE;   // 8

__global__ __launch_bounds__(BLOCK) void sbvr_decode_kernel(
        const float* __restrict__ coeff_cache,   // [65536, 4]
        const int*   __restrict__ coeff_idx,     // [G]
        const int*   __restrict__ bvr,           // [G, 4]
        float*       __restrict__ out)           // [G * 16]
{
    __shared__ f32x4 lds_c[2][G_TILE];   // gathered coeffs, 2 x 4 KB
    __shared__ i32x4 lds_b[2][G_TILE];   // bit words,       2 x 4 KB

    const int tid   = threadIdx.x;
    const int gbase = blockIdx.x * G_PER_BLK;

    // ---- prologue: stage tile 0 ----
    int   idx = __builtin_nontemporal_load(coeff_idx + (gbase + tid));
    i32x4 b   = __builtin_nontemporal_load((const i32x4*)bvr + (gbase + tid));
    f32x4 c   = ((const f32x4*)coeff_cache)[idx];   // cached: 1 MB table
    lds_c[0][tid] = c;
    lds_b[0][tid] = b;
    __syncthreads();

#pragma unroll 1
    for (int t = 0; t < TILES; ++t) {
        const int cur = t & 1;

        // ---- stage t+1: issue loads now, land during compute(t) ----
        if (t + 1 < TILES) {
            const int g = gbase + (t + 1) * G_TILE + tid;
            idx = __builtin_nontemporal_load(coeff_idx + g);
            b   = __builtin_nontemporal_load((const i32x4*)bvr + g);
            c   = ((const f32x4*)coeff_cache)[idx];  // waits only on idx
        }

        // ---- compute tile t from LDS, 4 contiguous store passes ----
        const int o0 = (gbase + t * G_TILE) * 4;     // f32x4 index
#pragma unroll
        for (int p = 0; p < 4; ++p) {
            const int gl = p * 64 + (tid >> 2);      // local group
            const int q4 = (tid & 3) * 4;            // first bit index

            const f32x4 cc = lds_c[cur][gl];         // 4-lane broadcast: free
            const i32x4 bb = lds_b[cur][gl];

            f32x4 r;
#pragma unroll
            for (int j = 0; j < 4; ++j) {
                const int l = q4 + j;
                // accumulate in the reference's s-order (s = 0..3) in fp32
                float acc = ((bb.x >> l) & 1) ? cc.x : 0.0f;
                acc      += ((bb.y >> l) & 1) ? cc.y : 0.0f;
                acc      += ((bb.z >> l) & 1) ? cc.z : 0.0f;
                acc      += ((bb.w >> l) & 1) ? cc.w : 0.0f;
                r[j] = acc;
            }
            __builtin_nontemporal_store(r, (f32x4*)out + (o0 + p * BLOCK + tid));
        }

        // ---- commit staged regs to the other buffer ----
        if (t + 1 < TILES) {
            lds_c[cur ^ 1][tid] = c;
            lds_b[cur ^ 1][tid] = b;
            __syncthreads();
        }
    }
}

extern "C" void kernel_launch(void* const* d_in, const int* in_sizes, int n_in,
                              void* d_out, int out_size, void* d_ws, size_t ws_size,
                              hipStream_t stream) {
    const float* coeff_cache = (const float*)d_in[0];
    const int*   coeff_idx   = (const int*)d_in[1];
    const int*   bvr         = (const int*)d_in[2];
    float*       out         = (float*)d_out;

    sbvr_decode_kernel<<<GRID, BLOCK, 0, stream>>>(coeff_cache, coeff_idx, bvr, out);
}

// Round 7
// 335.362 us; speedup vs baseline: 1.0076x; 1.0076x over previous
//
#include <hip/hip_runtime.h>

// sbvr decode: decoded[g,l] = sum_s coeff_cache[coeff_idx[g], s] * ((bvr[g,s]>>l)&1)
// G = 4,194,304 groups, S = 4 sums, L = 16 elements/group, out = 64M fp32 (256 MB).
//
// v9: v6 (cooperative staging, best at T_k~82us) + PLAIN CACHED STORES.
// Evidence chain: every NT-store version writes at 2.6-3.1 TB/s; the harness
// fill writes the SAME buffer at 6.4 TB/s with cached stores; v5's repeat
// passes (reads ~all LLC-resident, FETCH 49 MB/pass) were a near-pure write
// workload and STILL wrote at 2.65 TB/s -> the `nt` flag is the invariant
// suspect: no-allocate stores bypass L2/LLC and hit DRAM as unmerged
// sub-burst writes (~half burst efficiency), while cached stores merge to
// full lines in LLC. v3's cached-store regression was a confound: its 16
// addr/group structure let the 256 MB store stream thrash the coeff table
// out of L2/LLC, inflating gather traffic; v6's dedup (1 merged gather per
// group, 64x reuse per table line) cuts that exposure 4x.
// Single variable vs v6: __builtin_nontemporal_store -> plain store.
// Loads stay NT (no-allocate protects the L2-resident table from the
// idx/bvr streams); gather stays cached.
//
// NOTE: __builtin_nontemporal_* requires native ext_vector_type, not the
// HIP_vector_type structs (int4/float4) — hence i32x4/f32x4 below.

#define NUM_SUMS 4
#define BVR_LEN 16

typedef int   i32x4 __attribute__((ext_vector_type(4)));
typedef float f32x4 __attribute__((ext_vector_type(4)));

static constexpr int NUM_GROUPS = (8192 * 8192) / 16;  // 4,194,304
static constexpr int BLOCK      = 256;
static constexpr int G_BLK      = 256;                 // groups staged per block
static constexpr int GRID       = NUM_GROUPS / G_BLK;  // 16,384 blocks

__global__ __launch_bounds__(BLOCK) void sbvr_decode_kernel(
        const float* __restrict__ coeff_cache,   // [65536, 4]
        const int*   __restrict__ coeff_idx,     // [G]
        const int*   __restrict__ bvr,           // [G, 4]
        float*       __restrict__ out)           // [G * 16]
{
    __shared__ f32x4 lds_c[G_BLK];   // gathered coeffs, 4 KB
    __shared__ i32x4 lds_b[G_BLK];   // bit words,        4 KB

    const int tid = threadIdx.x;
    const int g0  = blockIdx.x * G_BLK;

    // ---- Phase A: cooperative stage, one lane per group ----
    {
        const int g = g0 + tid;
        // Streams read exactly once -> nontemporal (keep table L2-resident).
        const int   idx = __builtin_nontemporal_load(coeff_idx + g);
        const i32x4 b   = __builtin_nontemporal_load((const i32x4*)bvr + g);
        // Random 16 B gather: normal cached load (1 MB table, L2-resident).
        const f32x4 c   = ((const f32x4*)coeff_cache)[idx];
        lds_c[tid] = c;
        lds_b[tid] = b;
    }
    __syncthreads();

    // ---- Phase B: 4 passes, quarter-group per thread, contiguous stores ----
#pragma unroll
    for (int p = 0; p < 4; ++p) {
        const int gl = p * 64 + (tid >> 2);   // local group
        const int q4 = (tid & 3) * 4;         // first bit index

        const f32x4 c = lds_c[gl];            // 4-lane broadcast: free
        const i32x4 b = lds_b[gl];

        f32x4 r;
#pragma unroll
        for (int j = 0; j < 4; ++j) {
            const int l = q4 + j;
            // accumulate in the reference's s-order (s = 0..3) in fp32
            float acc = ((b.x >> l) & 1) ? c.x : 0.0f;
            acc      += ((b.y >> l) & 1) ? c.y : 0.0f;
            acc      += ((b.z >> l) & 1) ? c.z : 0.0f;
            acc      += ((b.w >> l) & 1) ? c.w : 0.0f;
            r[j] = acc;
        }
        // out4 index: (g0+gl)*4 + q = g0*4 + p*256 + tid -> contiguous 4 KB/wave
        // PLAIN cached store: merged to full lines in L2/LLC, written back as
        // full bursts (the 6.4 TB/s fill path), unlike nt sub-burst writes.
        ((f32x4*)out)[g0 * 4 + p * BLOCK + tid] = r;
    }
}

extern "C" void kernel_launch(void* const* d_in, const int* in_sizes, int n_in,
                              void* d_out, int out_size, void* d_ws, size_t ws_size,
                              hipStream_t stream) {
    const float* coeff_cache = (const float*)d_in[0];
    const int*   coeff_idx   = (const int*)d_in[1];
    const int*   bvr         = (const int*)d_in[2];
    float*       out         = (float*)d_out;

    sbvr_decode_kernel<<<GRID, BLOCK, 0, stream>>>(coeff_cache, coeff_idx, bvr, out);
}